// Round 6
// baseline (228.574 us; speedup 1.0000x reference)
//
#include <hip/hip_runtime.h>

typedef unsigned short u16;
typedef unsigned int u32;
typedef u16 u16x8 __attribute__((ext_vector_type(8)));
typedef u32 u32x4 __attribute__((ext_vector_type(4)));
typedef __bf16 bf16x8 __attribute__((ext_vector_type(8)));
typedef float f32x4 __attribute__((ext_vector_type(4)));
typedef float f32x16 __attribute__((ext_vector_type(16)));

#define DM 1024
#define SEQ 2048
#define BATCH 2
#define MROWS 4096  // BATCH * SEQ

__device__ __forceinline__ u16 f2bf(float f) {  // round-to-nearest-even
  unsigned int x = __builtin_bit_cast(unsigned int, f);
  x += 0x7fffu + ((x >> 16) & 1u);
  return (u16)(x >> 16);
}

// async global->LDS, 16B per lane; LDS dest = wave-uniform base + lane*16.
__device__ __forceinline__ void gld16(const void* g, void* l) {
  __builtin_amdgcn_global_load_lds(
      (const __attribute__((address_space(1))) void*)g,
      (__attribute__((address_space(3))) void*)l, 16, 0, 0);
}

// pack two f32 -> one u32 of 2 bf16 (low = lo), RNE.  No builtin (m240).
__device__ __forceinline__ u32 cvtpk_bf16(float lo, float hi) {
  u32 r;
  asm("v_cvt_pk_bf16_f32 %0, %1, %2" : "=v"(r) : "v"(lo), "v"(hi));
  return r;
}
// swap x's upper 32 lanes with y's lower 32 lanes (both regs modified).
__device__ __forceinline__ void pl32swap(u32& x, u32& y) {
  asm volatile("v_permlane32_swap_b32 %0, %1" : "+v"(x), "+v"(y));
}

// ---------------------------------------------------------------------------
// Fused 4x weight transpose + f32->bf16: out[n][k] = in[k][n], z picks weight.
// ---------------------------------------------------------------------------
struct TrArgs { const float* in[4]; u16* out[4]; };

__global__ __launch_bounds__(256) void transpose_w4(TrArgs a) {
  const float* __restrict__ in = a.in[blockIdx.z];
  u16* __restrict__ out = a.out[blockIdx.z];
  __shared__ u16 T[64][72];
  int r0 = blockIdx.y * 64, c0 = blockIdx.x * 64;
  int t = threadIdx.x;
  int r = t >> 3, cg = (t & 7) * 8;
#pragma unroll
  for (int p = 0; p < 2; p++) {
    const float* src = in + (size_t)(r0 + r + p * 32) * DM + c0 + cg;
    f32x4 x0 = *(const f32x4*)src;
    f32x4 x1 = *(const f32x4*)(src + 4);
    u16x8 v;
#pragma unroll
    for (int j = 0; j < 4; j++) { v[j] = f2bf(x0[j]); v[4 + j] = f2bf(x1[j]); }
    *(u16x8*)(&T[r + p * 32][cg]) = v;
  }
  __syncthreads();
#pragma unroll
  for (int p = 0; p < 2; p++) {
    int orow = r + p * 32;
    u16x8 v;
#pragma unroll
    for (int j = 0; j < 8; j++) v[j] = T[cg + j][orow];
    *(u16x8*)(out + (size_t)(c0 + orow) * DM + r0 + cg) = v;
  }
}

// ---------------------------------------------------------------------------
// Elementwise f32 -> bf16 cast for the three activation tensors.
// ---------------------------------------------------------------------------
struct CastArgs { const float* in[3]; u16* out[3]; };

__global__ __launch_bounds__(256) void cast_x(CastArgs a) {
  const float* __restrict__ in = a.in[blockIdx.y];
  u16* __restrict__ out = a.out[blockIdx.y];
  size_t e = ((size_t)blockIdx.x * 256 + threadIdx.x) * 8;
  f32x4 a0 = *(const f32x4*)(in + e);
  f32x4 a1 = *(const f32x4*)(in + e + 4);
  u16x8 v;
#pragma unroll
  for (int j = 0; j < 4; j++) { v[j] = f2bf(a0[j]); v[4 + j] = f2bf(a1[j]); }
  *(u16x8*)(out + e) = v;
}

// ---------------------------------------------------------------------------
// Tiled GEMM: C[M,1024] = A @ W + bias (fp32 acc, bf16 MFMA 16x16x32).
// Tile = (MT*32) x (NT*32); 4 waves in 2x2 quadrants of (MT*16)x(NT*16).
// BK=32; gld16 staging with source-side chunk swizzle (slot c ^ ((row>>1)&3)).
// blockIdx.z selects an (A, WT, bias, C) tuple (QKV fusion).
// ---------------------------------------------------------------------------
struct GemmArgs { const void* A[3]; const u16* WT[3]; const float* bias[3]; void* C[3]; };

template <int MT, int NT, bool AF32, bool OF32>
__global__ __launch_bounds__(256) void gemmT(GemmArgs g) {
  __shared__ __align__(16) u16 As[MT * 32 * 32];
  __shared__ __align__(16) u16 Bs[NT * 32 * 32];
  const int z = blockIdx.z;
  const u16* __restrict__ WT = g.WT[z];
  const int tid = threadIdx.x;
  const int lane = tid & 63, wave = tid >> 6;
  const int fr = lane & 15, kq = lane >> 4;
  const int mq = (wave >> 1) * (MT * 16), nq = (wave & 1) * (NT * 16);
  const int m0 = blockIdx.y * (MT * 32), n0 = blockIdx.x * (NT * 32);
  const int srow = tid >> 2;
  const int scA = ((tid & 3) ^ ((srow >> 1) & 3)) * 8;  // swizzled source col
  const int fco = ((kq ^ ((fr >> 1) & 3)) * 8);         // swizzled frag col
  f32x4 acc[MT][NT] = {};

  for (int kk = 0; kk < DM; kk += 32) {
    __syncthreads();  // previous tile fully consumed
    if constexpr (AF32) {
      const float* A = (const float*)g.A[z];
#pragma unroll
      for (int i = 0; i < MT / 2; i++) {
        const float* s0 = A + (size_t)(m0 + i * 64 + srow) * DM + kk + scA;
        f32x4 a0 = *(const f32x4*)s0, a1 = *(const f32x4*)(s0 + 4);
        u16x8 v;
#pragma unroll
        for (int j = 0; j < 4; j++) { v[j] = f2bf(a0[j]); v[4 + j] = f2bf(a1[j]); }
        *(u16x8*)(As + (i * 256 + tid) * 8) = v;
      }
    } else {
      const u16* A = (const u16*)g.A[z];
#pragma unroll
      for (int i = 0; i < MT / 2; i++)
        gld16(A + (size_t)(m0 + i * 64 + srow) * DM + kk + scA,
              As + (i * 256 + tid) * 8);
    }
#pragma unroll
    for (int i = 0; i < NT / 2; i++)
      gld16(WT + (size_t)(n0 + i * 64 + srow) * DM + kk + scA,
            Bs + (i * 256 + tid) * 8);
    __syncthreads();
    bf16x8 af[MT], bfr[NT];
#pragma unroll
    for (int mt = 0; mt < MT; mt++)
      af[mt] = __builtin_bit_cast(
          bf16x8, *(const u16x8*)(As + (mq + mt * 16 + fr) * 32 + fco));
#pragma unroll
    for (int nt = 0; nt < NT; nt++)
      bfr[nt] = __builtin_bit_cast(
          bf16x8, *(const u16x8*)(Bs + (nq + nt * 16 + fr) * 32 + fco));
#pragma unroll
    for (int mt = 0; mt < MT; mt++)
#pragma unroll
      for (int nt = 0; nt < NT; nt++)
        acc[mt][nt] =
            __builtin_amdgcn_mfma_f32_16x16x32_bf16(af[mt], bfr[nt], acc[mt][nt], 0, 0, 0);
  }
  const float* __restrict__ bias = g.bias[z];
#pragma unroll
  for (int nt = 0; nt < NT; nt++) {
    int col = n0 + nq + nt * 16 + fr;
    float bb = bias[col];
#pragma unroll
    for (int mt = 0; mt < MT; mt++)
#pragma unroll
      for (int r = 0; r < 4; r++) {
        int row = m0 + mq + mt * 16 + kq * 4 + r;
        float val = acc[mt][nt][r] + bb;
        if constexpr (OF32)
          ((float*)g.C[z])[(size_t)row * DM + col] = val;
        else
          ((u16*)g.C[z])[(size_t)row * DM + col] = f2bf(val);
      }
  }
}

// ---------------------------------------------------------------------------
// MFMA causal flash attention, 32x32 / in-register-P variant (V7).
// Scores s ~ N(0,1) after the 1/8 scale, so p = exp2(s*C1) never overflows.
//
// V5/V6 analysis: kernel is LDS-READ bound; 16x16 MFMA forces every wave to
// re-read full K/V tiles at half the arithmetic intensity of 32x32, and P
// round-trips through LDS.  V7 (guide Sec B structure, T12):
//  - Wave owns 32 q-rows; block = 4 waves = 128 q-rows.  All MFMA are
//    32x32x16 (C/D: col=lane&31, row=(r&3)+8*(r>>2)+4*(lane>>5); A: row=
//    lane&31, k=(lane>>5)*8+j; B: col=lane&31, k=(lane>>5)*8+j).
//  - SWAPPED QK^T: s = mfma(K, Q) -> lane holds S^T[key=crow][q=lane&31].
//    P stays IN REGISTERS: per 16-key slab, 4x v_cvt_pk_bf16_f32 +
//    2x v_permlane32_swap_b32 produce the PV A-fragment exactly
//    (own keys (0,1),(2,3)+4hi; partner supplies the other half; after
//    swap word order = keys (0,1)(2,3)(4,5)(6,7) per hi-slice).  No P LDS.
//  - l via ones B-operand into a third accumulator; l is lane-local per
//    q-row (every column equal).
//  - K chunk-swizzle + gld16 staging, b16 V-scatter (2-way free), dbuf
//    single-barrier pipeline: unchanged from V5 (proven).
// Grid: x = b*16+h (32), y: qt = 15 - y (LPT).  O in-place into Q.
// ---------------------------------------------------------------------------
#define KS 72
__global__ __launch_bounds__(256) void attn3(u16* __restrict__ Q,
                                             const u16* __restrict__ K,
                                             const u16* __restrict__ V) {
  __shared__ __align__(16) u16 Ksh[2][64 * 64];  // [key][depth], chunk-swizzled
  __shared__ __align__(16) u16 Vt[2][64 * KS];   // [depth][key]
  const int tid = threadIdx.x, wave = tid >> 6, lane = tid & 63;
  const int ql = lane & 31, hi = lane >> 5;
  const int b = blockIdx.x >> 4, h = blockIdx.x & 15;
  const int qt = 15 - blockIdx.y;  // LPT dispatch order
  const int tmax = 2 * qt + 1;
  const float C1 = 0.125f * 1.44269504f;

  // K staging: chunk (row, c) stored at slot c ^ (row&7)
  const int krow = tid >> 3;
  const int kcs = ((tid & 7) ^ (krow & 7)) * 8;
  const u16* Kg = K + (size_t)(b * SEQ + krow) * DM + h * 64 + kcs;
  // V: thread loads key-row `lane`, depth cols wave*16..+16 (16B)
  const u16* Vg = V + (size_t)(b * SEQ + lane) * DM + h * 64 + wave * 16;

  // K-frag swizzled slot offset (u16 units) per depth-frag f:
  // chunk c = 2f+hi, slot = c ^ (key&7); key&7 == ql&7 (tile keys mod 8).
  int xsl[4];
#pragma unroll
  for (int f = 0; f < 4; f++) xsl[f] = ((2 * f + hi) ^ (ql & 7)) * 8;

  bf16x8 qf[4];
  {
    size_t qr = (size_t)(b * SEQ + qt * 128 + wave * 32 + ql) * DM + h * 64;
#pragma unroll
    for (int f = 0; f < 4; f++)
      qf[f] = __builtin_bit_cast(bf16x8,
                                 *(const u16x8*)(Q + qr + f * 16 + hi * 8));
  }

  u16x8 onesu;
#pragma unroll
  for (int j = 0; j < 8; j++) onesu[j] = 0x3F80;
  const bf16x8 vones = __builtin_bit_cast(bf16x8, onesu);

  f32x16 ov0 = {}, ov1 = {}, ovl = {};

  // prologue: stage tile 0 into buffer 0
  gld16(Kg, Ksh[0] + tid * 8);
  gld16(Kg + (size_t)32 * DM, Ksh[0] + (256 + tid) * 8);
  {
    u16x8 v0 = *(const u16x8*)(Vg);
    u16x8 v1 = *(const u16x8*)(Vg + 8);
#pragma unroll
    for (int j = 0; j < 8; j++) {
      Vt[0][(wave * 16 + j) * KS + lane] = v0[j];
      Vt[0][(wave * 16 + 8 + j) * KS + lane] = v1[j];
    }
  }
  __syncthreads();

  int cur = 0;
  for (int t = 0; t <= tmax; t++) {
    const int nb = cur ^ 1;
    u16x8 nv0, nv1;
    const bool pf = (t < tmax);
    if (pf) {  // issue tile t+1 staging (async; lands in buffer nb)
      size_t ro = (size_t)(t + 1) * 64 * DM;
      gld16(Kg + ro, Ksh[nb] + tid * 8);
      gld16(Kg + ro + (size_t)32 * DM, Ksh[nb] + (256 + tid) * 8);
      nv0 = *(const u16x8*)(Vg + ro);
      nv1 = *(const u16x8*)(Vg + ro + 8);
    }
    const u16* Kc = Ksh[cur];
    // S^T = K.Q^T : two 32x32 key-tiles, 4 depth-frags each
    f32x16 s0 = {}, s1 = {};
#pragma unroll
    for (int f = 0; f < 4; f++) {
      bf16x8 a0 = __builtin_bit_cast(
          bf16x8, *(const u16x8*)(Kc + ql * 64 + xsl[f]));
      s0 = __builtin_amdgcn_mfma_f32_32x32x16_bf16(a0, qf[f], s0, 0, 0, 0);
      bf16x8 a1 = __builtin_bit_cast(
          bf16x8, *(const u16x8*)(Kc + (32 + ql) * 64 + xsl[f]));
      s1 = __builtin_amdgcn_mfma_f32_32x32x16_bf16(a1, qf[f], s1, 0, 0, 0);
    }
    if (t >= 2 * qt) {  // diagonal band: causal mask (key > q)
      int qg = qt * 128 + wave * 32 + ql;
      int kb = t * 64 + 4 * hi;
#pragma unroll
      for (int r = 0; r < 16; r++) {
        int key = kb + (r & 3) + 8 * (r >> 2);
        if (key > qg) s0[r] = -1e30f;
        if (key + 32 > qg) s1[r] = -1e30f;
      }
    }
    // P in registers: exp2 -> cvt_pk -> permlane32_swap -> PV MFMA
    const u16* Vc = Vt[cur];
#define DO_NT(SV, KB)                                                        \
  {                                                                          \
    float p[16];                                                             \
    _Pragma("unroll") for (int r = 0; r < 16; r++)                           \
        p[r] = __builtin_amdgcn_exp2f(SV[r] * C1);                           \
    _Pragma("unroll") for (int s = 0; s < 2; s++) {                          \
      u32 w0 = cvtpk_bf16(p[s * 8 + 0], p[s * 8 + 1]);                       \
      u32 w1 = cvtpk_bf16(p[s * 8 + 2], p[s * 8 + 3]);                       \
      u32 w2 = cvtpk_bf16(p[s * 8 + 4], p[s * 8 + 5]);                       \
      u32 w3 = cvtpk_bf16(p[s * 8 + 6], p[s * 8 + 7]);                       \
      pl32swap(w0, w2);                                                      \
      pl32swap(w1, w3);                                                      \
      u32x4 paw = {w0, w1, w2, w3};                                          \
      bf16x8 pa = __builtin_bit_cast(bf16x8, paw);                           \
      const int kb2 = (KB) + s * 16 + hi * 8;                                \
      bf16x8 vb0 = __builtin_bit_cast(                                       \
          bf16x8, *(const u16x8*)(Vc + ql * KS + kb2));                      \
      ov0 = __builtin_amdgcn_mfma_f32_32x32x16_bf16(pa, vb0, ov0, 0, 0, 0);  \
      bf16x8 vb1 = __builtin_bit_cast(                                       \
          bf16x8, *(const u16x8*)(Vc + (32 + ql) * KS + kb2));               \
      ov1 = __builtin_amdgcn_mfma_f32_32x32x16_bf16(pa, vb1, ov1, 0, 0, 0);  \
      ovl = __builtin_amdgcn_mfma_f32_32x32x16_bf16(pa, vones, ovl, 0, 0, 0); \
    }                                                                        \
  }
    DO_NT(s0, 0)
    DO_NT(s1, 32)
#undef DO_NT
    if (pf) {  // scatter-transpose V(t+1) into Vt[nb]
#pragma unroll
      for (int j = 0; j < 8; j++) {
        Vt[nb][(wave * 16 + j) * KS + lane] = nv0[j];
        Vt[nb][(wave * 16 + 8 + j) * KS + lane] = nv1[j];
      }
    }
    __syncthreads();  // drains prefetch issued a full compute-phase ago
    cur = nb;
  }
  // epilogue: O = ov / l, in-place into Q (l lane-local: every col of ovl = l)
  float rinv[16];
#pragma unroll
  for (int r = 0; r < 16; r++) rinv[r] = 1.0f / ovl[r];
#pragma unroll
  for (int r = 0; r < 16; r++) {
    int row = qt * 128 + wave * 32 + (r & 3) + 8 * (r >> 2) + 4 * hi;
    size_t base = (size_t)(b * SEQ + row) * DM + h * 64 + ql;
    Q[base] = f2bf(ov0[r] * rinv[r]);
    Q[base + 32] = f2bf(ov1[r] * rinv[r]);
  }
}

// ---------------------------------------------------------------------------
extern "C" void kernel_launch(void* const* d_in, const int* in_sizes, int n_in,
                              void* d_out, int out_size, void* d_ws,
                              size_t ws_size, hipStream_t stream) {
  const float* xk = (const float*)d_in[0];
  const float* xq = (const float*)d_in[1];
  const float* xv = (const float*)d_in[2];
  const float* wq = (const float*)d_in[3];
  const float* bq = (const float*)d_in[4];
  const float* wk = (const float*)d_in[5];
  const float* bk = (const float*)d_in[6];
  const float* wv = (const float*)d_in[7];
  const float* bv = (const float*)d_in[8];
  const float* wo = (const float*)d_in[9];
  const float* bo = (const float*)d_in[10];

  u16* Qb = (u16*)d_ws;                       // Q, then attention O (in-place)
  u16* Kb = Qb + (size_t)MROWS * DM;
  u16* Vb = Kb + (size_t)MROWS * DM;
  u16* WTq = Vb + (size_t)MROWS * DM;
  u16* WTk = WTq + (size_t)DM * DM;
  u16* WTv = WTk + (size_t)DM * DM;
  u16* WTo = WTv + (size_t)DM * DM;
  u16* Xq = WTo + (size_t)DM * DM;            // cast-path only
  u16* Xk = Xq + (size_t)MROWS * DM;
  u16* Xv = Xk + (size_t)MROWS * DM;
  const bool cast_path =
      ws_size >= ((size_t)(3 * 8 + 4 * 2 + 3 * 8)) * 1024 * 1024;

  dim3 blk(256);

  TrArgs tr;
  tr.in[0] = wq; tr.in[1] = wk; tr.in[2] = wv; tr.in[3] = wo;
  tr.out[0] = WTq; tr.out[1] = WTk; tr.out[2] = WTv; tr.out[3] = WTo;
  transpose_w4<<<dim3(16, 16, 4), blk, 0, stream>>>(tr);

  GemmArgs gq;
  gq.WT[0] = WTq; gq.WT[1] = WTk; gq.WT[2] = WTv;
  gq.bias[0] = bq; gq.bias[1] = bk; gq.bias[2] = bv;
  gq.C[0] = Qb; gq.C[1] = Kb; gq.C[2] = Vb;
  if (cast_path) {
    CastArgs ca;
    ca.in[0] = xq; ca.in[1] = xk; ca.in[2] = xv;
    ca.out[0] = Xq; ca.out[1] = Xk; ca.out[2] = Xv;
    cast_x<<<dim3(MROWS * DM / 2048, 3), blk, 0, stream>>>(ca);
    gq.A[0] = Xq; gq.A[1] = Xk; gq.A[2] = Xv;
    gemmT<4, 4, false, false>
        <<<dim3(DM / 128, MROWS / 128, 3), blk, 0, stream>>>(gq);
  } else {
    gq.A[0] = xq; gq.A[1] = xk; gq.A[2] = xv;
    gemmT<4, 4, true, false>
        <<<dim3(DM / 128, MROWS / 128, 3), blk, 0, stream>>>(gq);
  }

  attn3<<<dim3(BATCH * 16, 16), blk, 0, stream>>>(Qb, Kb, Vb);

  GemmArgs go;
  go.A[0] = Qb;  go.WT[0] = WTo; go.bias[0] = bo; go.C[0] = d_out;
  go.A[1] = Qb;  go.WT[1] = WTo; go.bias[1] = bo; go.C[1] = d_out;
  go.A[2] = Qb;  go.WT[2] = WTo; go.bias[2] = bo; go.C[2] = d_out;
  gemmT<2, 4, false, true>
      <<<dim3(DM / 128, MROWS / 64, 1), blk, 0, stream>>>(go);
}

// Round 7
// 223.571 us; speedup vs baseline: 1.0224x; 1.0224x over previous
//
#include <hip/hip_runtime.h>

typedef unsigned short u16;
typedef unsigned int u32;
typedef u16 u16x8 __attribute__((ext_vector_type(8)));
typedef u32 u32x4 __attribute__((ext_vector_type(4)));
typedef __bf16 bf16x8 __attribute__((ext_vector_type(8)));
typedef float f32x4 __attribute__((ext_vector_type(4)));
typedef float f32x16 __attribute__((ext_vector_type(16)));

#define DM 1024
#define SEQ 2048
#define BATCH 2
#define MROWS 4096  // BATCH * SEQ

__device__ __forceinline__ u16 f2bf(float f) {  // round-to-nearest-even
  unsigned int x = __builtin_bit_cast(unsigned int, f);
  x += 0x7fffu + ((x >> 16) & 1u);
  return (u16)(x >> 16);
}

// async global->LDS, 16B per lane; LDS dest = wave-uniform base + lane*16.
__device__ __forceinline__ void gld16(const void* g, void* l) {
  __builtin_amdgcn_global_load_lds(
      (const __attribute__((address_space(1))) void*)g,
      (__attribute__((address_space(3))) void*)l, 16, 0, 0);
}

// pack two f32 -> one u32 of 2 bf16 (low = lo), RNE.  No builtin (m240).
__device__ __forceinline__ u32 cvtpk_bf16(float lo, float hi) {
  u32 r;
  asm("v_cvt_pk_bf16_f32 %0, %1, %2" : "=v"(r) : "v"(lo), "v"(hi));
  return r;
}
// swap x's upper 32 lanes with y's lower 32 lanes (both regs modified).
__device__ __forceinline__ void pl32swap(u32& x, u32& y) {
  asm volatile("v_permlane32_swap_b32 %0, %1" : "+v"(x), "+v"(y));
}

// ---------------------------------------------------------------------------
// Fused 4x weight transpose + f32->bf16: out[n][k] = in[k][n], z picks weight.
// ---------------------------------------------------------------------------
struct TrArgs { const float* in[4]; u16* out[4]; };

__global__ __launch_bounds__(256) void transpose_w4(TrArgs a) {
  const float* __restrict__ in = a.in[blockIdx.z];
  u16* __restrict__ out = a.out[blockIdx.z];
  __shared__ u16 T[64][72];
  int r0 = blockIdx.y * 64, c0 = blockIdx.x * 64;
  int t = threadIdx.x;
  int r = t >> 3, cg = (t & 7) * 8;
#pragma unroll
  for (int p = 0; p < 2; p++) {
    const float* src = in + (size_t)(r0 + r + p * 32) * DM + c0 + cg;
    f32x4 x0 = *(const f32x4*)src;
    f32x4 x1 = *(const f32x4*)(src + 4);
    u16x8 v;
#pragma unroll
    for (int j = 0; j < 4; j++) { v[j] = f2bf(x0[j]); v[4 + j] = f2bf(x1[j]); }
    *(u16x8*)(&T[r + p * 32][cg]) = v;
  }
  __syncthreads();
#pragma unroll
  for (int p = 0; p < 2; p++) {
    int orow = r + p * 32;
    u16x8 v;
#pragma unroll
    for (int j = 0; j < 8; j++) v[j] = T[cg + j][orow];
    *(u16x8*)(out + (size_t)(c0 + orow) * DM + r0 + cg) = v;
  }
}

// ---------------------------------------------------------------------------
// Elementwise f32 -> bf16 cast for the three activation tensors.
// ---------------------------------------------------------------------------
struct CastArgs { const float* in[3]; u16* out[3]; };

__global__ __launch_bounds__(256) void cast_x(CastArgs a) {
  const float* __restrict__ in = a.in[blockIdx.y];
  u16* __restrict__ out = a.out[blockIdx.y];
  size_t e = ((size_t)blockIdx.x * 256 + threadIdx.x) * 8;
  f32x4 a0 = *(const f32x4*)(in + e);
  f32x4 a1 = *(const f32x4*)(in + e + 4);
  u16x8 v;
#pragma unroll
  for (int j = 0; j < 4; j++) { v[j] = f2bf(a0[j]); v[4 + j] = f2bf(a1[j]); }
  *(u16x8*)(out + e) = v;
}

// ---------------------------------------------------------------------------
// Tiled GEMM: C[M,1024] = A @ W + bias (fp32 acc, bf16 MFMA 16x16x32).
// Tile = (MT*32) x (NT*32); 4 waves in 2x2 quadrants of (MT*16)x(NT*16).
// BK=32; gld16 staging with source-side chunk swizzle (slot c ^ ((row>>1)&3)).
// blockIdx.z selects an (A, WT, bias, C) tuple (QKV fusion).
// ---------------------------------------------------------------------------
struct GemmArgs { const void* A[3]; const u16* WT[3]; const float* bias[3]; void* C[3]; };

template <int MT, int NT, bool AF32, bool OF32>
__global__ __launch_bounds__(256) void gemmT(GemmArgs g) {
  __shared__ __align__(16) u16 As[MT * 32 * 32];
  __shared__ __align__(16) u16 Bs[NT * 32 * 32];
  const int z = blockIdx.z;
  const u16* __restrict__ WT = g.WT[z];
  const int tid = threadIdx.x;
  const int lane = tid & 63, wave = tid >> 6;
  const int fr = lane & 15, kq = lane >> 4;
  const int mq = (wave >> 1) * (MT * 16), nq = (wave & 1) * (NT * 16);
  const int m0 = blockIdx.y * (MT * 32), n0 = blockIdx.x * (NT * 32);
  const int srow = tid >> 2;
  const int scA = ((tid & 3) ^ ((srow >> 1) & 3)) * 8;  // swizzled source col
  const int fco = ((kq ^ ((fr >> 1) & 3)) * 8);         // swizzled frag col
  f32x4 acc[MT][NT] = {};

  for (int kk = 0; kk < DM; kk += 32) {
    __syncthreads();  // previous tile fully consumed
    if constexpr (AF32) {
      const float* A = (const float*)g.A[z];
#pragma unroll
      for (int i = 0; i < MT / 2; i++) {
        const float* s0 = A + (size_t)(m0 + i * 64 + srow) * DM + kk + scA;
        f32x4 a0 = *(const f32x4*)s0, a1 = *(const f32x4*)(s0 + 4);
        u16x8 v;
#pragma unroll
        for (int j = 0; j < 4; j++) { v[j] = f2bf(a0[j]); v[4 + j] = f2bf(a1[j]); }
        *(u16x8*)(As + (i * 256 + tid) * 8) = v;
      }
    } else {
      const u16* A = (const u16*)g.A[z];
#pragma unroll
      for (int i = 0; i < MT / 2; i++)
        gld16(A + (size_t)(m0 + i * 64 + srow) * DM + kk + scA,
              As + (i * 256 + tid) * 8);
    }
#pragma unroll
    for (int i = 0; i < NT / 2; i++)
      gld16(WT + (size_t)(n0 + i * 64 + srow) * DM + kk + scA,
            Bs + (i * 256 + tid) * 8);
    __syncthreads();
    bf16x8 af[MT], bfr[NT];
#pragma unroll
    for (int mt = 0; mt < MT; mt++)
      af[mt] = __builtin_bit_cast(
          bf16x8, *(const u16x8*)(As + (mq + mt * 16 + fr) * 32 + fco));
#pragma unroll
    for (int nt = 0; nt < NT; nt++)
      bfr[nt] = __builtin_bit_cast(
          bf16x8, *(const u16x8*)(Bs + (nq + nt * 16 + fr) * 32 + fco));
#pragma unroll
    for (int mt = 0; mt < MT; mt++)
#pragma unroll
      for (int nt = 0; nt < NT; nt++)
        acc[mt][nt] =
            __builtin_amdgcn_mfma_f32_16x16x32_bf16(af[mt], bfr[nt], acc[mt][nt], 0, 0, 0);
  }
  const float* __restrict__ bias = g.bias[z];
#pragma unroll
  for (int nt = 0; nt < NT; nt++) {
    int col = n0 + nq + nt * 16 + fr;
    float bb = bias[col];
#pragma unroll
    for (int mt = 0; mt < MT; mt++)
#pragma unroll
      for (int r = 0; r < 4; r++) {
        int row = m0 + mq + mt * 16 + kq * 4 + r;
        float val = acc[mt][nt][r] + bb;
        if constexpr (OF32)
          ((float*)g.C[z])[(size_t)row * DM + col] = val;
        else
          ((u16*)g.C[z])[(size_t)row * DM + col] = f2bf(val);
      }
  }
}

// ---------------------------------------------------------------------------
// MFMA causal flash attention V8: V7's verified 32x32/in-register-P inner
// loop + V5's verified fold, combined via KEY-SPLIT wave-pairs.
//
// V7 post-mortem: inner loop fine (conflicts 2.7M->1.1M) but 512 triangular
// 128-row blocks decayed occupancy to 11.8% (3.8 waves/CU).  V5's fold
// sustained ~6.3 waves/CU but with the fat 16x16 inner loop.  V8:
//  - q-tile = 64 rows; block = 4 waves.  pair=wave>>1 splits each 64-key
//    tile's KEYS (pair0: 0-31, pair1: 32-63); w01=wave&1 splits q-rows.
//    Per tile each wave runs exactly half of V7's tile body: 4 QK MFMAs +
//    one DO_NT (same cvt_pk + permlane32_swap A-frag build, mask with
//    kb += pair*32).  Staging/dbuf/gld16/V-scatter byte-identical to V7.
//  - Fold: pass0 qt=31-y, pass1 qt=y -> 33 tiles/block UNIFORM; 512 blocks
//    = 2/CU = 8 waves/CU sustained (pair-split absorbed the fold's 2x).
//  - Per-pass combine: pair1 writes partial (ov0,ov1,ovl: 48 f32/lane) to a
//    dedicated LDS scratch; one barrier; pair0 adds + epilogue.  LDS 59.9KB.
// Grid: x = b*16+h (32), y in 0..15.  O in-place into Q.
// ---------------------------------------------------------------------------
#define KS 72
__global__ __launch_bounds__(256) void attn3(u16* __restrict__ Q,
                                             const u16* __restrict__ K,
                                             const u16* __restrict__ V) {
  __shared__ __align__(16) u16 Ksh[2][64 * 64];  // [key][depth], chunk-swizzled
  __shared__ __align__(16) u16 Vt[2][64 * KS];   // [depth][key]
  __shared__ float cmb[128][49];                 // pair1 partials (pad 49)
  const int tid = threadIdx.x, wave = tid >> 6, lane = tid & 63;
  const int ql = lane & 31, hi = lane >> 5;
  const int pair = wave >> 1, w01 = wave & 1;
  const int b = blockIdx.x >> 4, h = blockIdx.x & 15;
  const int y = blockIdx.y;
  const float C1 = 0.125f * 1.44269504f;

  // K staging: chunk (row, c) stored at slot c ^ (row&7)
  const int krow = tid >> 3;
  const int kcs = ((tid & 7) ^ (krow & 7)) * 8;
  const u16* Kg = K + (size_t)(b * SEQ + krow) * DM + h * 64 + kcs;
  // V: thread loads key-row `lane`, depth cols wave*16..+16 (16B)
  const u16* Vg = V + (size_t)(b * SEQ + lane) * DM + h * 64 + wave * 16;

  // K-frag swizzled slot offset (u16 units) per depth-frag f (key&7 == ql&7)
  int xsl[4];
#pragma unroll
  for (int f = 0; f < 4; f++) xsl[f] = ((2 * f + hi) ^ (ql & 7)) * 8;

  u16x8 onesu;
#pragma unroll
  for (int j = 0; j < 8; j++) onesu[j] = 0x3F80;
  const bf16x8 vones = __builtin_bit_cast(bf16x8, onesu);

  for (int pass = 0; pass < 2; pass++) {
    const int qt = pass ? y : 31 - y;  // 64-row q-tile index, keys < (qt+1)*64

    bf16x8 qf[4];
    {
      size_t qr = (size_t)(b * SEQ + qt * 64 + w01 * 32 + ql) * DM + h * 64;
#pragma unroll
      for (int f = 0; f < 4; f++)
        qf[f] = __builtin_bit_cast(bf16x8,
                                   *(const u16x8*)(Q + qr + f * 16 + hi * 8));
    }

    f32x16 ov0 = {}, ov1 = {}, ovl = {};

    // prologue: stage tile 0 into buffer 0
    gld16(Kg, Ksh[0] + tid * 8);
    gld16(Kg + (size_t)32 * DM, Ksh[0] + (256 + tid) * 8);
    {
      u16x8 v0 = *(const u16x8*)(Vg);
      u16x8 v1 = *(const u16x8*)(Vg + 8);
#pragma unroll
      for (int j = 0; j < 8; j++) {
        Vt[0][(wave * 16 + j) * KS + lane] = v0[j];
        Vt[0][(wave * 16 + 8 + j) * KS + lane] = v1[j];
      }
    }
    __syncthreads();

    int cur = 0;
    for (int t = 0; t <= qt; t++) {
      const int nb = cur ^ 1;
      u16x8 nv0, nv1;
      const bool pf = (t < qt);
      if (pf) {  // issue tile t+1 staging (async; lands in buffer nb)
        size_t ro = (size_t)(t + 1) * 64 * DM;
        gld16(Kg + ro, Ksh[nb] + tid * 8);
        gld16(Kg + ro + (size_t)32 * DM, Ksh[nb] + (256 + tid) * 8);
        nv0 = *(const u16x8*)(Vg + ro);
        nv1 = *(const u16x8*)(Vg + ro + 8);
      }
      const u16* Kc = Ksh[cur];
      // S^T = K.Q^T for this pair's 32 keys (key = pair*32 + crow)
      f32x16 s = {};
#pragma unroll
      for (int f = 0; f < 4; f++) {
        bf16x8 a0 = __builtin_bit_cast(
            bf16x8, *(const u16x8*)(Kc + (pair * 32 + ql) * 64 + xsl[f]));
        s = __builtin_amdgcn_mfma_f32_32x32x16_bf16(a0, qf[f], s, 0, 0, 0);
      }
      if (t == qt) {  // diagonal tile: causal mask (key > q)
        int qg = qt * 64 + w01 * 32 + ql;
        int kb = t * 64 + pair * 32 + 4 * hi;
#pragma unroll
        for (int r = 0; r < 16; r++) {
          int key = kb + (r & 3) + 8 * (r >> 2);
          if (key > qg) s[r] = -1e30f;
        }
      }
      // P in registers: exp2 -> cvt_pk -> permlane32_swap -> PV MFMA
      const u16* Vc = Vt[cur];
      {
        float p[16];
#pragma unroll
        for (int r = 0; r < 16; r++)
          p[r] = __builtin_amdgcn_exp2f(s[r] * C1);
#pragma unroll
        for (int ss = 0; ss < 2; ss++) {
          u32 w0 = cvtpk_bf16(p[ss * 8 + 0], p[ss * 8 + 1]);
          u32 w1 = cvtpk_bf16(p[ss * 8 + 2], p[ss * 8 + 3]);
          u32 w2 = cvtpk_bf16(p[ss * 8 + 4], p[ss * 8 + 5]);
          u32 w3 = cvtpk_bf16(p[ss * 8 + 6], p[ss * 8 + 7]);
          pl32swap(w0, w2);
          pl32swap(w1, w3);
          u32x4 paw = {w0, w1, w2, w3};
          bf16x8 pa = __builtin_bit_cast(bf16x8, paw);
          const int kb2 = pair * 32 + ss * 16 + hi * 8;
          bf16x8 vb0 = __builtin_bit_cast(
              bf16x8, *(const u16x8*)(Vc + ql * KS + kb2));
          ov0 = __builtin_amdgcn_mfma_f32_32x32x16_bf16(pa, vb0, ov0, 0, 0, 0);
          bf16x8 vb1 = __builtin_bit_cast(
              bf16x8, *(const u16x8*)(Vc + (32 + ql) * KS + kb2));
          ov1 = __builtin_amdgcn_mfma_f32_32x32x16_bf16(pa, vb1, ov1, 0, 0, 0);
          ovl = __builtin_amdgcn_mfma_f32_32x32x16_bf16(pa, vones, ovl, 0, 0, 0);
        }
      }
      if (pf) {  // scatter-transpose V(t+1) into Vt[nb]
#pragma unroll
        for (int j = 0; j < 8; j++) {
          Vt[nb][(wave * 16 + j) * KS + lane] = nv0[j];
          Vt[nb][(wave * 16 + 8 + j) * KS + lane] = nv1[j];
        }
      }
      __syncthreads();  // drains prefetch issued a full compute-phase ago
      cur = nb;
    }
    // combine: pair1 -> LDS scratch; pair0 adds + epilogue
    if (pair == 1) {
      float* dst = cmb[w01 * 64 + lane];
#pragma unroll
      for (int r = 0; r < 16; r++) {
        dst[r] = ov0[r];
        dst[16 + r] = ov1[r];
        dst[32 + r] = ovl[r];
      }
    }
    __syncthreads();
    if (pair == 0) {
      const float* src = cmb[w01 * 64 + lane];
#pragma unroll
      for (int r = 0; r < 16; r++) {
        ov0[r] += src[r];
        ov1[r] += src[16 + r];
        ovl[r] += src[32 + r];
      }
      float rinv[16];
#pragma unroll
      for (int r = 0; r < 16; r++) rinv[r] = 1.0f / ovl[r];
#pragma unroll
      for (int r = 0; r < 16; r++) {
        int row = qt * 64 + w01 * 32 + (r & 3) + 8 * (r >> 2) + 4 * hi;
        size_t base = (size_t)(b * SEQ + row) * DM + h * 64 + ql;
        Q[base] = f2bf(ov0[r] * rinv[r]);
        Q[base + 32] = f2bf(ov1[r] * rinv[r]);
      }
    }
    __syncthreads();  // scratch free before next pass
  }
}

// ---------------------------------------------------------------------------
extern "C" void kernel_launch(void* const* d_in, const int* in_sizes, int n_in,
                              void* d_out, int out_size, void* d_ws,
                              size_t ws_size, hipStream_t stream) {
  const float* xk = (const float*)d_in[0];
  const float* xq = (const float*)d_in[1];
  const float* xv = (const float*)d_in[2];
  const float* wq = (const float*)d_in[3];
  const float* bq = (const float*)d_in[4];
  const float* wk = (const float*)d_in[5];
  const float* bk = (const float*)d_in[6];
  const float* wv = (const float*)d_in[7];
  const float* bv = (const float*)d_in[8];
  const float* wo = (const float*)d_in[9];
  const float* bo = (const float*)d_in[10];

  u16* Qb = (u16*)d_ws;                       // Q, then attention O (in-place)
  u16* Kb = Qb + (size_t)MROWS * DM;
  u16* Vb = Kb + (size_t)MROWS * DM;
  u16* WTq = Vb + (size_t)MROWS * DM;
  u16* WTk = WTq + (size_t)DM * DM;
  u16* WTv = WTk + (size_t)DM * DM;
  u16* WTo = WTv + (size_t)DM * DM;
  u16* Xq = WTo + (size_t)DM * DM;            // cast-path only
  u16* Xk = Xq + (size_t)MROWS * DM;
  u16* Xv = Xk + (size_t)MROWS * DM;
  const bool cast_path =
      ws_size >= ((size_t)(3 * 8 + 4 * 2 + 3 * 8)) * 1024 * 1024;

  dim3 blk(256);

  TrArgs tr;
  tr.in[0] = wq; tr.in[1] = wk; tr.in[2] = wv; tr.in[3] = wo;
  tr.out[0] = WTq; tr.out[1] = WTk; tr.out[2] = WTv; tr.out[3] = WTo;
  transpose_w4<<<dim3(16, 16, 4), blk, 0, stream>>>(tr);

  GemmArgs gq;
  gq.WT[0] = WTq; gq.WT[1] = WTk; gq.WT[2] = WTv;
  gq.bias[0] = bq; gq.bias[1] = bk; gq.bias[2] = bv;
  gq.C[0] = Qb; gq.C[1] = Kb; gq.C[2] = Vb;
  if (cast_path) {
    CastArgs ca;
    ca.in[0] = xq; ca.in[1] = xk; ca.in[2] = xv;
    ca.out[0] = Xq; ca.out[1] = Xk; ca.out[2] = Xv;
    cast_x<<<dim3(MROWS * DM / 2048, 3), blk, 0, stream>>>(ca);
    gq.A[0] = Xq; gq.A[1] = Xk; gq.A[2] = Xv;
    gemmT<4, 4, false, false>
        <<<dim3(DM / 128, MROWS / 128, 3), blk, 0, stream>>>(gq);
  } else {
    gq.A[0] = xq; gq.A[1] = xk; gq.A[2] = xv;
    gemmT<4, 4, true, false>
        <<<dim3(DM / 128, MROWS / 128, 3), blk, 0, stream>>>(gq);
  }

  attn3<<<dim3(BATCH * 16, 16), blk, 0, stream>>>(Qb, Kb, Vb);

  GemmArgs go;
  go.A[0] = Qb;  go.WT[0] = WTo; go.bias[0] = bo; go.C[0] = d_out;
  go.A[1] = Qb;  go.WT[1] = WTo; go.bias[1] = bo; go.C[1] = d_out;
  go.A[2] = Qb;  go.WT[2] = WTo; go.bias[2] = bo; go.C[2] = d_out;
  gemmT<2, 4, false, true>
      <<<dim3(DM / 128, MROWS / 64, 1), blk, 0, stream>>>(go);
}